// Round 1
// baseline (232.779 us; speedup 1.0000x reference)
//
#include <hip/hip_runtime.h>
#include <hip/hip_bf16.h>

#define N_ROWS 4096
#define C_CLS  1000
#define C_PAD  1024
#define A_DIM  2048

typedef __attribute__((ext_vector_type(8))) short short8;
typedef __attribute__((ext_vector_type(4))) float f32x4;

__device__ __forceinline__ unsigned short f2bf(float x) {
    unsigned u = __float_as_uint(x);
    unsigned rounding = 0x7fffu + ((u >> 16) & 1u);
    return (unsigned short)((u + rounding) >> 16);
}

__device__ __forceinline__ unsigned pack2(float a, float b) {
    return (unsigned)f2bf(a) | ((unsigned)f2bf(b) << 16);
}

// ---------------- prep W: bf16 W and W^2, padded to C_PAD rows with zeros ----
__global__ __launch_bounds__(256) void prep_w(const float* __restrict__ W,
                                              unsigned short* __restrict__ Wb,
                                              unsigned short* __restrict__ W2b) {
    int t = blockIdx.x * 256 + threadIdx.x;   // each thread: 4 elements
    int a4 = t * 4;
    int c = a4 >> 11;          // / 2048
    int a = a4 & (A_DIM - 1);
    float4 w = make_float4(0.f, 0.f, 0.f, 0.f);
    if (c < C_CLS) w = *(const float4*)(W + (size_t)c * A_DIM + a);
    uint2 pw, pw2;
    pw.x  = pack2(w.x, w.y);             pw.y  = pack2(w.z, w.w);
    pw2.x = pack2(w.x * w.x, w.y * w.y); pw2.y = pack2(w.z * w.z, w.w * w.w);
    *(uint2*)(Wb  + (size_t)a4) = pw;
    *(uint2*)(W2b + (size_t)a4) = pw2;
}

// ---------------- prep A operands: Fb, Ub = f - r*cv*wy, Vb = 0.5r*cv, t3c ---
__global__ __launch_bounds__(256) void prep_a(const float* __restrict__ F,
                                              const float* __restrict__ CV,
                                              const float* __restrict__ W,
                                              const int* __restrict__ labels,
                                              const float* __restrict__ ratio_p,
                                              unsigned short* __restrict__ Fb,
                                              unsigned short* __restrict__ Ub,
                                              unsigned short* __restrict__ Vb,
                                              float* __restrict__ t3c) {
    int n = blockIdx.x;
    int y = labels[n];
    float ratio = ratio_p[0];
    float hr = 0.5f * ratio;
    const float* frow  = F  + (size_t)n * A_DIM;
    const float* cvrow = CV + (size_t)n * A_DIM;
    const float* wyrow = W  + (size_t)y * A_DIM;
    size_t obase = (size_t)n * A_DIM;
    float s = 0.f;
    #pragma unroll
    for (int seg = 0; seg < 2; seg++) {
        int a = (threadIdx.x + seg * 256) * 4;
        float4 f  = *(const float4*)(frow + a);
        float4 cv = *(const float4*)(cvrow + a);
        float4 wy = *(const float4*)(wyrow + a);
        float u0 = f.x - ratio * cv.x * wy.x;
        float u1 = f.y - ratio * cv.y * wy.y;
        float u2 = f.z - ratio * cv.z * wy.z;
        float u3 = f.w - ratio * cv.w * wy.w;
        s += wy.x * wy.x * cv.x + wy.y * wy.y * cv.y
           + wy.z * wy.z * cv.z + wy.w * wy.w * cv.w;
        uint2 pf, pu, pv;
        pf.x = pack2(f.x, f.y);               pf.y = pack2(f.z, f.w);
        pu.x = pack2(u0, u1);                 pu.y = pack2(u2, u3);
        pv.x = pack2(hr * cv.x, hr * cv.y);   pv.y = pack2(hr * cv.z, hr * cv.w);
        *(uint2*)(Fb + obase + a) = pf;
        *(uint2*)(Ub + obase + a) = pu;
        *(uint2*)(Vb + obase + a) = pv;
    }
    // block-reduce s
    for (int off = 32; off; off >>= 1) s += __shfl_down(s, off);
    __shared__ float wsum[4];
    int lane = threadIdx.x & 63, wid = threadIdx.x >> 6;
    if (lane == 0) wsum[wid] = s;
    __syncthreads();
    if (threadIdx.x == 0)
        t3c[n] = hr * (wsum[0] + wsum[1] + wsum[2] + wsum[3]);
}

// ---------------- fused triple-GEMM: logits + aug --------------------------
#define BM 128
#define BN 128
#define BK 32
#define LDSP 40   // padded LDS row stride (ushorts): 80B rows, 16B-aligned frags

__global__ __launch_bounds__(512) void gemm_fused(
        const unsigned short* __restrict__ Fb, const unsigned short* __restrict__ Ub,
        const unsigned short* __restrict__ Vb, const unsigned short* __restrict__ Wb,
        const unsigned short* __restrict__ W2b,
        const float* __restrict__ t3c, const float* __restrict__ bias,
        float* __restrict__ out_logits, float* __restrict__ aug) {
    __shared__ unsigned short sF[BM * LDSP];
    __shared__ unsigned short sU[BM * LDSP];
    __shared__ unsigned short sV[BM * LDSP];
    __shared__ unsigned short sW[BN * LDSP];
    __shared__ unsigned short sW2[BN * LDSP];

    int bn = blockIdx.x, bm = blockIdx.y;
    int tid = threadIdx.x;
    int lane = tid & 63, wid = tid >> 6;
    int wm = wid >> 2, wn = wid & 3;        // 2 x 4 wave grid, 64x32 per wave

    int sr = tid >> 2;            // 0..127
    int sc = (tid & 3) * 8;       // 0,8,16,24
    size_t gA = (size_t)(bm * BM + sr) * A_DIM + sc;
    size_t gB = (size_t)(bn * BN + sr) * A_DIM + sc;
    int sdst = sr * LDSP + sc;

    f32x4 accL[4][2] = {};
    f32x4 accA[4][2] = {};

    int fr_row = lane & 15;
    int fr_k   = (lane >> 4) * 8;

    for (int k0 = 0; k0 < A_DIM; k0 += BK) {
        uint4 vF  = *(const uint4*)(Fb  + gA + k0);
        uint4 vU  = *(const uint4*)(Ub  + gA + k0);
        uint4 vV  = *(const uint4*)(Vb  + gA + k0);
        uint4 vW  = *(const uint4*)(Wb  + gB + k0);
        uint4 vW2 = *(const uint4*)(W2b + gB + k0);
        __syncthreads();
        *(uint4*)(sF  + sdst) = vF;
        *(uint4*)(sU  + sdst) = vU;
        *(uint4*)(sV  + sdst) = vV;
        *(uint4*)(sW  + sdst) = vW;
        *(uint4*)(sW2 + sdst) = vW2;
        __syncthreads();

        short8 aF[4], aU[4], aV[4], bW[2], bW2[2];
        #pragma unroll
        for (int m = 0; m < 4; m++) {
            int row = wm * 64 + m * 16 + fr_row;
            aF[m] = *(const short8*)(sF + row * LDSP + fr_k);
            aU[m] = *(const short8*)(sU + row * LDSP + fr_k);
            aV[m] = *(const short8*)(sV + row * LDSP + fr_k);
        }
        #pragma unroll
        for (int n = 0; n < 2; n++) {
            int row = wn * 32 + n * 16 + fr_row;
            bW[n]  = *(const short8*)(sW  + row * LDSP + fr_k);
            bW2[n] = *(const short8*)(sW2 + row * LDSP + fr_k);
        }
        #pragma unroll
        for (int m = 0; m < 4; m++)
            #pragma unroll
            for (int n = 0; n < 2; n++) {
                accL[m][n] = __builtin_amdgcn_mfma_f32_16x16x32_bf16(aF[m], bW[n],  accL[m][n], 0, 0, 0);
                accA[m][n] = __builtin_amdgcn_mfma_f32_16x16x32_bf16(aU[m], bW[n],  accA[m][n], 0, 0, 0);
                accA[m][n] = __builtin_amdgcn_mfma_f32_16x16x32_bf16(aV[m], bW2[n], accA[m][n], 0, 0, 0);
            }
    }

    // epilogue: logits -> d_out+1 ([N,1000]); aug -> ws ([N,1024], only c<1000)
    #pragma unroll
    for (int n = 0; n < 2; n++) {
        int col = bn * BN + wn * 32 + n * 16 + (lane & 15);
        if (col >= C_CLS) continue;
        float bv = bias[col];
        #pragma unroll
        for (int m = 0; m < 4; m++) {
            int rbase = bm * BM + wm * 64 + m * 16 + (lane >> 4) * 4;
            #pragma unroll
            for (int j = 0; j < 4; j++) {
                int row = rbase + j;
                out_logits[(size_t)row * C_CLS + col] = accL[m][n][j] + bv;
                aug[(size_t)row * C_PAD + col] = accA[m][n][j] + bv + t3c[row];
            }
        }
    }
}

// ---------------- per-row softmax NLL ---------------------------------------
__global__ __launch_bounds__(256) void softmax_nll(const float* __restrict__ aug,
                                                   const int* __restrict__ labels,
                                                   float* __restrict__ nll) {
    int n = blockIdx.x;
    const float* row = aug + (size_t)n * C_PAD;
    int lane = threadIdx.x & 63, wid = threadIdx.x >> 6;
    __shared__ float sm[4], ss[4];

    float mx = -1e30f;
    for (int c = threadIdx.x; c < C_CLS; c += 256) mx = fmaxf(mx, row[c]);
    for (int off = 32; off; off >>= 1) mx = fmaxf(mx, __shfl_down(mx, off));
    if (lane == 0) sm[wid] = mx;
    __syncthreads();
    mx = fmaxf(fmaxf(sm[0], sm[1]), fmaxf(sm[2], sm[3]));

    float s = 0.f;
    for (int c = threadIdx.x; c < C_CLS; c += 256) s += __expf(row[c] - mx);
    for (int off = 32; off; off >>= 1) s += __shfl_down(s, off);
    if (lane == 0) ss[wid] = s;
    __syncthreads();
    if (threadIdx.x == 0) {
        float tot = ss[0] + ss[1] + ss[2] + ss[3];
        nll[n] = logf(tot) + mx - row[labels[n]];
    }
}

__global__ __launch_bounds__(256) void final_reduce(const float* __restrict__ nll,
                                                    float* __restrict__ out_loss) {
    float s = 0.f;
    for (int i = threadIdx.x; i < N_ROWS; i += 256) s += nll[i];
    for (int off = 32; off; off >>= 1) s += __shfl_down(s, off);
    __shared__ float ss[4];
    int lane = threadIdx.x & 63, wid = threadIdx.x >> 6;
    if (lane == 0) ss[wid] = s;
    __syncthreads();
    if (threadIdx.x == 0)
        out_loss[0] = (ss[0] + ss[1] + ss[2] + ss[3]) / (float)N_ROWS;
}

// ---------------- launch -----------------------------------------------------
extern "C" void kernel_launch(void* const* d_in, const int* in_sizes, int n_in,
                              void* d_out, int out_size, void* d_ws, size_t ws_size,
                              hipStream_t stream) {
    const float* features = (const float*)d_in[0];
    const int*   labels   = (const int*)d_in[1];
    const float* cv       = (const float*)d_in[2];
    const float* ratio    = (const float*)d_in[3];
    const float* weight   = (const float*)d_in[4];
    const float* bias     = (const float*)d_in[5];
    float* out = (float*)d_out;

    char* p = (char*)d_ws;
    unsigned short* Wb  = (unsigned short*)p; p += (size_t)C_PAD * A_DIM * 2;
    unsigned short* W2b = (unsigned short*)p; p += (size_t)C_PAD * A_DIM * 2;
    unsigned short* Fb  = (unsigned short*)p; p += (size_t)N_ROWS * A_DIM * 2;
    unsigned short* Ub  = (unsigned short*)p; p += (size_t)N_ROWS * A_DIM * 2;
    unsigned short* Vb  = (unsigned short*)p; p += (size_t)N_ROWS * A_DIM * 2;
    float* t3c   = (float*)p; p += (size_t)N_ROWS * 4;
    float* aug   = (float*)p; p += (size_t)N_ROWS * C_PAD * 4;
    float* nllb  = (float*)p; p += (size_t)N_ROWS * 4;

    prep_w<<<(C_PAD * A_DIM / 4) / 256, 256, 0, stream>>>(weight, Wb, W2b);
    prep_a<<<N_ROWS, 256, 0, stream>>>(features, cv, weight, labels, ratio,
                                       Fb, Ub, Vb, t3c);
    gemm_fused<<<dim3(C_PAD / BN, N_ROWS / BM), 512, 0, stream>>>(
        Fb, Ub, Vb, Wb, W2b, t3c, bias, out + 1, aug);
    softmax_nll<<<N_ROWS, 256, 0, stream>>>(aug, labels, nllb);
    final_reduce<<<1, 256, 0, stream>>>(nllb, out);
}